// Round 12
// baseline (343.788 us; speedup 1.0000x reference)
//
#include <hip/hip_runtime.h>
#include <hip/hip_bf16.h>

// Round 12 = ABLATION. Answer via proven r9 pipeline (absmax 0.0039), then
// four REP=16 diagnostics that only touch ws scratch (fully overwritten by
// the answer pipeline at the start of each replay -> deterministic, safe):
//   kd_stream: flat stream-read of u      -> measures machine-deliverable BW
//   kd_stage : kbig-geometry staging only -> read-path suspect
//   kd_mfma  : + phase1 MFMA + softmax    -> compute add-on
//   kd_wr    : tpart writes only          -> write-path suspect
// Top-5 rocprof rows will rank them above the 59us kbigs.

#define BB 64
#define NN 2048
#define DD 64
#define II 32
#define CHROWS 128
#define NCH (NN / CHROWS)
#define REP 16

typedef __attribute__((ext_vector_type(8)))  short bf16x8;
typedef __attribute__((ext_vector_type(16))) float f32x16;

__device__ __forceinline__ short f2bf(float f) {
    __hip_bfloat16 h = __float2bfloat16(f);
    return *reinterpret_cast<short*>(&h);
}
__device__ __forceinline__ float bf2f(short s) {
    __hip_bfloat16 h = *reinterpret_cast<__hip_bfloat16*>(&s);
    return __bfloat162float(h);
}
__device__ __forceinline__ int sw(int row, int d) { return d ^ ((row & 7) << 3); }

// ---------------- kernel 1: spart[cb][b][d] = sum of 64 rows ----------------
__global__ __launch_bounds__(256) void ksum(const float* __restrict__ u,
                                            float* __restrict__ spart) {
    int b = blockIdx.y, cb = blockIdx.x;
    int tid = threadIdx.x, cg = tid & 15, rr = tid >> 4;
    const float4* up = reinterpret_cast<const float4*>(
        u + ((size_t)b * NN + (size_t)cb * 64 + rr) * DD) + cg;
    float4 a = {0.f, 0.f, 0.f, 0.f};
    #pragma unroll
    for (int k = 0; k < 4; ++k) {
        float4 v = up[(size_t)k * 16 * (DD / 4)];
        a.x += v.x; a.y += v.y; a.z += v.z; a.w += v.w;
    }
    __shared__ float4 red[16][16];
    red[rr][cg] = a;
    __syncthreads();
    if (rr == 0) {
        float4 s = red[0][cg];
        #pragma unroll
        for (int r = 1; r < 16; ++r) {
            s.x += red[r][cg].x; s.y += red[r][cg].y;
            s.z += red[r][cg].z; s.w += red[r][cg].w;
        }
        reinterpret_cast<float4*>(spart + ((size_t)cb * BB + b) * DD)[cg] = s;
    }
}

// ---------------- small kernel ----------------
template <int MODE>
__global__ __launch_bounds__(512) void ksmall(const float* __restrict__ src,
                                              const float* __restrict__ W,
                                              float* __restrict__ w_out,
                                              float* __restrict__ out) {
    int b = blockIdx.x;
    int tid = threadIdx.x;
    int i = tid >> 4;
    int j = tid & 15;
    __shared__ float srow[DD];
    if (MODE == 0) {
        if (tid < DD) {
            float a = 0.f;
            for (int cb = 0; cb < 32; ++cb)
                a += src[((size_t)cb * BB + b) * DD + tid];
            srow[tid] = a;
        }
        __syncthreads();
    }
    const float* trow = (MODE == 0) ? srow : (src + ((size_t)b * II + i) * DD);
    float o = 0.f;
    #pragma unroll 8
    for (int d = 0; d < DD; ++d)
        o += trow[d] * W[d * (II * 16) + i * 16 + j];
    if (MODE == 0) o *= (1.0f / 32.0f);

    float ss = o * o;
    #pragma unroll
    for (int off = 8; off >= 1; off >>= 1)
        ss += __shfl_xor(ss, off, 16);

    if (MODE == 2) {
        float s2 = ss + 1e-7f;
        float scale = sqrtf(s2) / (0.5f + s2);
        out[((size_t)b * II + i) * 16 + j] = scale * o;
        return;
    }

    float norm = sqrtf(fmaxf(ss, 1e-12f));
    float ov = o / norm;
    __shared__ float osh[II][16];
    osh[i][j] = ov;
    __syncthreads();
    #pragma unroll
    for (int k = 0; k < 4; ++k) {
        int d = j + 16 * k;
        float acc = 0.f;
        #pragma unroll
        for (int jj = 0; jj < 16; ++jj)
            acc += W[d * (II * 16) + i * 16 + jj] * osh[i][jj];
        w_out[((size_t)b * II + i) * DD + d] = acc;
    }
}

// ---------------- partial reduce ----------------
__global__ __launch_bounds__(256) void kred(const float* __restrict__ in,
                                            float* __restrict__ out) {
    int m = blockIdx.x * 256 + threadIdx.x;
    float acc = 0.f;
    #pragma unroll
    for (int ch = 0; ch < NCH; ++ch)
        acc += in[(size_t)ch * (BB * II * DD) + m];
    out[m] = acc;
}

// ---------------- big kernel (r9 verbatim) ----------------
__global__ __launch_bounds__(256) void kbig(const float* __restrict__ u,
                                            const float* __restrict__ w,
                                            float* __restrict__ tpart) {
    int b = blockIdx.y;
    int chunk = blockIdx.x;
    int tid = threadIdx.x;
    int wv = tid >> 6, l = tid & 63, h = l >> 5, ln = l & 31;

    __shared__ unsigned short uhi[CHROWS * DD];
    __shared__ unsigned short ulo[CHROWS * DD];
    __shared__ unsigned short whi[II * DD];
    __shared__ float cbuf[CHROWS][II + 1];

    const float4* ub4 = reinterpret_cast<const float4*>(
        u + ((size_t)b * NN + (size_t)chunk * CHROWS) * DD);
    #pragma unroll
    for (int k = 0; k < 8; ++k) {
        int gidx = k * 256 + tid;
        int row  = gidx >> 4;
        int d0   = (gidx & 15) * 4;
        float4 v = ub4[gidx];
        short h0=f2bf(v.x), h1=f2bf(v.y), h2=f2bf(v.z), h3=f2bf(v.w);
        short s0=f2bf(v.x-bf2f(h0)), s1=f2bf(v.y-bf2f(h1)),
              s2=f2bf(v.z-bf2f(h2)), s3=f2bf(v.w-bf2f(h3));
        int idx = row * DD + sw(row, d0);
        uint2 ph = { (unsigned)(unsigned short)h0 | ((unsigned)(unsigned short)h1 << 16),
                     (unsigned)(unsigned short)h2 | ((unsigned)(unsigned short)h3 << 16) };
        uint2 pl = { (unsigned)(unsigned short)s0 | ((unsigned)(unsigned short)s1 << 16),
                     (unsigned)(unsigned short)s2 | ((unsigned)(unsigned short)s3 << 16) };
        *reinterpret_cast<uint2*>(&uhi[idx]) = ph;
        *reinterpret_cast<uint2*>(&ulo[idx]) = pl;
    }
    const float4* wb4 = reinterpret_cast<const float4*>(w + (size_t)b * II * DD);
    #pragma unroll
    for (int k = 0; k < 2; ++k) {
        int gidx = k * 256 + tid;
        int row  = gidx >> 4;
        int d0   = (gidx & 15) * 4;
        float4 v = wb4[gidx];
        short h0=f2bf(v.x), h1=f2bf(v.y), h2=f2bf(v.z), h3=f2bf(v.w);
        int idx = row * DD + sw(row, d0);
        uint2 ph = { (unsigned)(unsigned short)h0 | ((unsigned)(unsigned short)h1 << 16),
                     (unsigned)(unsigned short)h2 | ((unsigned)(unsigned short)h3 << 16) };
        *reinterpret_cast<uint2*>(&whi[idx]) = ph;
    }
    __syncthreads();

    f32x16 S;
    #pragma unroll
    for (int r = 0; r < 16; ++r) S[r] = 0.f;
    int nloc = wv * 32 + ln;
    #pragma unroll
    for (int kt = 0; kt < 4; ++kt) {
        int d0 = kt * 16 + h * 8;
        bf16x8 A  = *reinterpret_cast<const bf16x8*>(&whi[ln * DD + sw(ln, d0)]);
        bf16x8 Bv = *reinterpret_cast<const bf16x8*>(&uhi[nloc * DD + sw(nloc, d0)]);
        S = __builtin_amdgcn_mfma_f32_32x32x16_bf16(A, Bv, S, 0, 0, 0);
    }

    float m = S[0];
    #pragma unroll
    for (int r = 1; r < 16; ++r) m = fmaxf(m, S[r]);
    m = fmaxf(m, __shfl_xor(m, 32));
    float sum = 0.f;
    float e[16];
    #pragma unroll
    for (int r = 0; r < 16; ++r) { e[r] = __expf(S[r] - m); sum += e[r]; }
    sum += __shfl_xor(sum, 32);
    float inv = 1.f / sum;
    #pragma unroll
    for (int r = 0; r < 16; ++r) {
        int irow = (r & 3) + 8 * (r >> 2) + 4 * h;
        cbuf[nloc][irow] = e[r] * inv;
    }
    __syncthreads();

    f32x16 G0, G1;
    #pragma unroll
    for (int r = 0; r < 16; ++r) { G0[r] = 0.f; G1[r] = 0.f; }

    bf16x8 Ah[2], Al[2];
    #pragma unroll
    for (int t2 = 0; t2 < 2; ++t2) {
        int nb = wv * 32 + t2 * 16 + h * 8;
        #pragma unroll
        for (int jj = 0; jj < 8; ++jj) {
            float cv = cbuf[nb + jj][ln];
            short hi = f2bf(cv);
            Ah[t2][jj] = hi;
            Al[t2][jj] = f2bf(cv - bf2f(hi));
        }
    }

    #pragma unroll
    for (int t2 = 0; t2 < 2; ++t2) {
        int nb = wv * 32 + t2 * 16 + h * 8;
        #pragma unroll
        for (int Nt = 0; Nt < 2; ++Nt) {
            bf16x8 Bh, Bl;
            #pragma unroll
            for (int jj = 0; jj < 8; ++jj) {
                int row = nb + jj;
                int idx = row * DD + sw(row, Nt * 32 + ln);
                Bh[jj] = (short)uhi[idx];
                Bl[jj] = (short)ulo[idx];
            }
            if (Nt == 0) {
                G0 = __builtin_amdgcn_mfma_f32_32x32x16_bf16(Ah[t2], Bh, G0, 0, 0, 0);
                G0 = __builtin_amdgcn_mfma_f32_32x32x16_bf16(Al[t2], Bh, G0, 0, 0, 0);
                G0 = __builtin_amdgcn_mfma_f32_32x32x16_bf16(Ah[t2], Bl, G0, 0, 0, 0);
            } else {
                G1 = __builtin_amdgcn_mfma_f32_32x32x16_bf16(Ah[t2], Bh, G1, 0, 0, 0);
                G1 = __builtin_amdgcn_mfma_f32_32x32x16_bf16(Al[t2], Bh, G1, 0, 0, 0);
                G1 = __builtin_amdgcn_mfma_f32_32x32x16_bf16(Ah[t2], Bl, G1, 0, 0, 0);
            }
        }
    }
    __syncthreads();

    float (*tlds)[65] = reinterpret_cast<float(*)[65]>(&cbuf[0][0]);
    for (int k = tid; k < II * 65; k += 256) (&tlds[0][0])[k] = 0.f;
    __syncthreads();
    #pragma unroll
    for (int r = 0; r < 16; ++r) {
        int irow = (r & 3) + 8 * (r >> 2) + 4 * h;
        atomicAdd(&tlds[irow][ln],      G0[r]);
        atomicAdd(&tlds[irow][32 + ln], G1[r]);
    }
    __syncthreads();
    float* dst = tpart + ((size_t)chunk * BB + b) * (II * DD);
    for (int k = tid; k < II * DD; k += 256)
        dst[k] = tlds[k >> 6][k & 63];
}

// ================= DIAGNOSTICS (REP passes each) =================

// D1: flat stream read of u — measures machine-deliverable bandwidth.
__global__ __launch_bounds__(256) void kd_stream(const float* __restrict__ u,
                                                 float* __restrict__ sink) {
    const float4* p = reinterpret_cast<const float4*>(u);
    const int n4 = BB * NN * DD / 4;
    float4 a = {0.f, 0.f, 0.f, 0.f};
    for (int rep = 0; rep < REP; ++rep) {
        for (int i = blockIdx.x * 256 + threadIdx.x; i < n4; i += 2048 * 256) {
            float4 v = p[i];
            a.x += v.x; a.y += v.y; a.z += v.z; a.w += v.w;
        }
    }
    sink[blockIdx.x * 256 + threadIdx.x] = a.x + a.y + a.z + a.w;
}

// D2: kbig-geometry staging only (same LDS footprint, same grid).
__global__ __launch_bounds__(256) void kd_stage(const float* __restrict__ u,
                                                float* __restrict__ sink) {
    int b = blockIdx.y, tid = threadIdx.x;
    __shared__ unsigned short uhi[CHROWS * DD];
    __shared__ unsigned short ulo[CHROWS * DD];
    __shared__ unsigned short whi[II * DD];
    __shared__ float cbuf[CHROWS][II + 1];
    (void)whi; (void)cbuf;
    float acc = 0.f;
    for (int rep = 0; rep < REP; ++rep) {
        int chunk = (int)((blockIdx.x + rep * 7) & (NCH - 1));
        const float4* ub4 = reinterpret_cast<const float4*>(
            u + ((size_t)b * NN + (size_t)chunk * CHROWS) * DD);
        #pragma unroll
        for (int k = 0; k < 8; ++k) {
            int gidx = k * 256 + tid;
            int row  = gidx >> 4;
            int d0   = (gidx & 15) * 4;
            float4 v = ub4[gidx];
            short h0=f2bf(v.x), h1=f2bf(v.y), h2=f2bf(v.z), h3=f2bf(v.w);
            short s0=f2bf(v.x-bf2f(h0)), s1=f2bf(v.y-bf2f(h1)),
                  s2=f2bf(v.z-bf2f(h2)), s3=f2bf(v.w-bf2f(h3));
            int idx = row * DD + sw(row, d0);
            uint2 ph = { (unsigned)(unsigned short)h0 | ((unsigned)(unsigned short)h1 << 16),
                         (unsigned)(unsigned short)h2 | ((unsigned)(unsigned short)h3 << 16) };
            uint2 pl = { (unsigned)(unsigned short)s0 | ((unsigned)(unsigned short)s1 << 16),
                         (unsigned)(unsigned short)s2 | ((unsigned)(unsigned short)s3 << 16) };
            *reinterpret_cast<uint2*>(&uhi[idx]) = ph;
            *reinterpret_cast<uint2*>(&ulo[idx]) = pl;
        }
        __syncthreads();
        acc += bf2f((short)uhi[tid]) + bf2f((short)ulo[tid + 256]);
        __syncthreads();
    }
    sink[((size_t)blockIdx.y * NCH + blockIdx.x) * 256 + tid] = acc;
}

// D3: staging + phase1 MFMA + softmax (the front half of kbig).
__global__ __launch_bounds__(256) void kd_mfma(const float* __restrict__ u,
                                               const float* __restrict__ w,
                                               float* __restrict__ sink) {
    int b = blockIdx.y, tid = threadIdx.x;
    int wv = tid >> 6, l = tid & 63, h = l >> 5, ln = l & 31;
    __shared__ unsigned short uhi[CHROWS * DD];
    __shared__ unsigned short ulo[CHROWS * DD];
    __shared__ unsigned short whi[II * DD];
    __shared__ float cbuf[CHROWS][II + 1];
    float acc = 0.f;
    for (int rep = 0; rep < REP; ++rep) {
        int chunk = (int)((blockIdx.x + rep * 7) & (NCH - 1));
        const float4* ub4 = reinterpret_cast<const float4*>(
            u + ((size_t)b * NN + (size_t)chunk * CHROWS) * DD);
        #pragma unroll
        for (int k = 0; k < 8; ++k) {
            int gidx = k * 256 + tid;
            int row  = gidx >> 4;
            int d0   = (gidx & 15) * 4;
            float4 v = ub4[gidx];
            short h0=f2bf(v.x), h1=f2bf(v.y), h2=f2bf(v.z), h3=f2bf(v.w);
            short s0=f2bf(v.x-bf2f(h0)), s1=f2bf(v.y-bf2f(h1)),
                  s2=f2bf(v.z-bf2f(h2)), s3=f2bf(v.w-bf2f(h3));
            int idx = row * DD + sw(row, d0);
            uint2 ph = { (unsigned)(unsigned short)h0 | ((unsigned)(unsigned short)h1 << 16),
                         (unsigned)(unsigned short)h2 | ((unsigned)(unsigned short)h3 << 16) };
            uint2 pl = { (unsigned)(unsigned short)s0 | ((unsigned)(unsigned short)s1 << 16),
                         (unsigned)(unsigned short)s2 | ((unsigned)(unsigned short)s3 << 16) };
            *reinterpret_cast<uint2*>(&uhi[idx]) = ph;
            *reinterpret_cast<uint2*>(&ulo[idx]) = pl;
        }
        const float4* wb4 = reinterpret_cast<const float4*>(w + (size_t)b * II * DD);
        #pragma unroll
        for (int k = 0; k < 2; ++k) {
            int gidx = k * 256 + tid;
            int row  = gidx >> 4;
            int d0   = (gidx & 15) * 4;
            float4 v = wb4[gidx];
            short h0=f2bf(v.x), h1=f2bf(v.y), h2=f2bf(v.z), h3=f2bf(v.w);
            int idx = row * DD + sw(row, d0);
            uint2 ph = { (unsigned)(unsigned short)h0 | ((unsigned)(unsigned short)h1 << 16),
                         (unsigned)(unsigned short)h2 | ((unsigned)(unsigned short)h3 << 16) };
            *reinterpret_cast<uint2*>(&whi[idx]) = ph;
        }
        __syncthreads();

        f32x16 S;
        #pragma unroll
        for (int r = 0; r < 16; ++r) S[r] = 0.f;
        int nloc = wv * 32 + ln;
        #pragma unroll
        for (int kt = 0; kt < 4; ++kt) {
            int d0 = kt * 16 + h * 8;
            bf16x8 A  = *reinterpret_cast<const bf16x8*>(&whi[ln * DD + sw(ln, d0)]);
            bf16x8 Bv = *reinterpret_cast<const bf16x8*>(&uhi[nloc * DD + sw(nloc, d0)]);
            S = __builtin_amdgcn_mfma_f32_32x32x16_bf16(A, Bv, S, 0, 0, 0);
        }
        float m = S[0];
        #pragma unroll
        for (int r = 1; r < 16; ++r) m = fmaxf(m, S[r]);
        m = fmaxf(m, __shfl_xor(m, 32));
        float sum = 0.f, e[16];
        #pragma unroll
        for (int r = 0; r < 16; ++r) { e[r] = __expf(S[r] - m); sum += e[r]; }
        sum += __shfl_xor(sum, 32);
        float inv = 1.f / sum;
        #pragma unroll
        for (int r = 0; r < 16; ++r) {
            int irow = (r & 3) + 8 * (r >> 2) + 4 * h;
            cbuf[(wv * 32 + ln)][irow] = e[r] * inv;
        }
        __syncthreads();
        acc += cbuf[tid & 127][tid & 31];
        __syncthreads();
    }
    sink[((size_t)blockIdx.y * NCH + blockIdx.x) * 256 + tid] = acc;
}

// D4: write-path only — the tpart store pattern.
__global__ __launch_bounds__(256) void kd_wr(float* __restrict__ tpart) {
    int b = blockIdx.y, tid = threadIdx.x;
    for (int rep = 0; rep < REP; ++rep) {
        int chunk = (int)((blockIdx.x + rep) & (NCH - 1));
        float* dst = tpart + ((size_t)chunk * BB + b) * (II * DD);
        for (int k = tid; k < II * DD; k += 256)
            dst[k] = (float)rep;
    }
}

extern "C" void kernel_launch(void* const* d_in, const int* in_sizes, int n_in,
                              void* d_out, int out_size, void* d_ws, size_t ws_size,
                              hipStream_t stream) {
    const float* u = (const float*)d_in[0];     // (64, 2048, 64)
    const float* W = (const float*)d_in[1];     // (1, 64, 512)
    float* out = (float*)d_out;                 // (64, 32, 16)
    float* ws = (float*)d_ws;

    float* t1    = ws;                          // 131072 floats
    float* wtil  = ws + 131072;                 // 131072
    float* spart = ws + 2 * 131072;             // 131072
    float* tpart = ws + 3 * 131072;             // NCH*131072 (8 MB) — also diag sink

    dim3 gbig(NCH, BB);
    // ---- answer (r9 proven pipeline) ----
    ksum<<<dim3(32, BB), 256, 0, stream>>>(u, spart);
    ksmall<0><<<BB, 512, 0, stream>>>(spart, W, wtil, nullptr);
    kbig<<<gbig, 256, 0, stream>>>(u, wtil, tpart);
    kred<<<BB * II * DD / 256, 256, 0, stream>>>(tpart, t1);
    ksmall<1><<<BB, 512, 0, stream>>>(t1, W, wtil, nullptr);
    kbig<<<gbig, 256, 0, stream>>>(u, wtil, tpart);
    kred<<<BB * II * DD / 256, 256, 0, stream>>>(tpart, t1);
    ksmall<2><<<BB, 512, 0, stream>>>(t1, W, nullptr, out);

    // ---- diagnostics (write only to tpart scratch; every replay's answer
    //      pipeline fully rewrites spart/tpart before reading them) ----
    kd_stream<<<2048, 256, 0, stream>>>(u, tpart);
    kd_stage<<<gbig, 256, 0, stream>>>(u, tpart);
    kd_mfma<<<gbig, 256, 0, stream>>>(u, wtil, tpart);
    kd_wr<<<gbig, 256, 0, stream>>>(tpart);
}

// Round 13
// 151.105 us; speedup vs baseline: 2.2752x; 2.2752x over previous
//
#include <hip/hip_runtime.h>
#include <hip/hip_bf16.h>

// Capsule dynamic routing, factored (no u_hat), MFMA, MINIMAL-LDS kbig.
// B=64, N=2048, D=64, I=32, J=16.
// r12 ablation: kd_mfma ran 16 kbig-front-half passes in 84us (5.25us/pass,
// 3.2 TB/s) while standalone kbig = 59us -> ~55us fixed per-dispatch cost.
// Fast dispatches (ksum 4KB, kred 0KB, kd_wr 0KB) vs slow (kbig 25-54KB,
// kall 118KB): covariate = LDS size. Test+exploit: kbig with 8.3 KB LDS.
//   phase1 un-swapped: C[n][i] = mfma(A=u rows, B=w~^T)  (global->reg frags)
//   softmax over i: cross-lane shfl reduce within 32-lane groups
//   phase2 A = c^T assembled in registers via one shfl_xor(.,32) per tile
//   phase2 B = u columns from global (r6 pattern)
//   LDS: only tlds[32][65] for the cross-wave t reduce.

#define BB 64
#define NN 2048
#define DD 64
#define II 32
#define CHROWS 128            // rows per kbig block (4 waves x 32 rows)
#define NCH (NN / CHROWS)     // 16 chunks per batch

typedef __attribute__((ext_vector_type(8)))  short bf16x8;
typedef __attribute__((ext_vector_type(16))) float f32x16;

__device__ __forceinline__ short f2bf(float f) {
    __hip_bfloat16 h = __float2bfloat16(f);
    return *reinterpret_cast<short*>(&h);
}
__device__ __forceinline__ float bf2f(short s) {
    __hip_bfloat16 h = *reinterpret_cast<__hip_bfloat16*>(&s);
    return __bfloat162float(h);
}

// ---------------- kernel 1: spart[cb][b][d] = sum of 64 rows ----------------
__global__ __launch_bounds__(256) void ksum(const float* __restrict__ u,
                                            float* __restrict__ spart) {
    int b = blockIdx.y, cb = blockIdx.x;
    int tid = threadIdx.x, cg = tid & 15, rr = tid >> 4;
    const float4* up = reinterpret_cast<const float4*>(
        u + ((size_t)b * NN + (size_t)cb * 64 + rr) * DD) + cg;
    float4 a = {0.f, 0.f, 0.f, 0.f};
    #pragma unroll
    for (int k = 0; k < 4; ++k) {
        float4 v = up[(size_t)k * 16 * (DD / 4)];
        a.x += v.x; a.y += v.y; a.z += v.z; a.w += v.w;
    }
    __shared__ float4 red[16][16];
    red[rr][cg] = a;
    __syncthreads();
    if (rr == 0) {
        float4 s = red[0][cg];
        #pragma unroll
        for (int r = 1; r < 16; ++r) {
            s.x += red[r][cg].x; s.y += red[r][cg].y;
            s.z += red[r][cg].z; s.w += red[r][cg].w;
        }
        reinterpret_cast<float4*>(spart + ((size_t)cb * BB + b) * DD)[cg] = s;
    }
}

// ---------------- small kernel: per-(b,i) o, normalize, w~ (or squash->out) ----
template <int MODE>
__global__ __launch_bounds__(512) void ksmall(const float* __restrict__ src,
                                              const float* __restrict__ W,
                                              float* __restrict__ w_out,
                                              float* __restrict__ out) {
    int b = blockIdx.x;
    int tid = threadIdx.x;
    int i = tid >> 4;
    int j = tid & 15;
    __shared__ float srow[DD];
    if (MODE == 0) {
        if (tid < DD) {
            float a = 0.f;
            for (int cb = 0; cb < 32; ++cb)
                a += src[((size_t)cb * BB + b) * DD + tid];
            srow[tid] = a;
        }
        __syncthreads();
    }
    const float* trow = (MODE == 0) ? srow : (src + ((size_t)b * II + i) * DD);
    float o = 0.f;
    #pragma unroll 8
    for (int d = 0; d < DD; ++d)
        o += trow[d] * W[d * (II * 16) + i * 16 + j];
    if (MODE == 0) o *= (1.0f / 32.0f);

    float ss = o * o;
    #pragma unroll
    for (int off = 8; off >= 1; off >>= 1)
        ss += __shfl_xor(ss, off, 16);

    if (MODE == 2) {
        float s2 = ss + 1e-7f;                       // K.epsilon
        float scale = sqrtf(s2) / (0.5f + s2);       // squash
        out[((size_t)b * II + i) * 16 + j] = scale * o;
        return;
    }

    float norm = sqrtf(fmaxf(ss, 1e-12f));           // tf l2_normalize
    float ov = o / norm;
    __shared__ float osh[II][16];
    osh[i][j] = ov;
    __syncthreads();
    #pragma unroll
    for (int k = 0; k < 4; ++k) {
        int d = j + 16 * k;
        float acc = 0.f;
        #pragma unroll
        for (int jj = 0; jj < 16; ++jj)
            acc += W[d * (II * 16) + i * 16 + jj] * osh[i][jj];
        w_out[((size_t)b * II + i) * DD + d] = acc;
    }
}

// ---------------- partial reduce: t[m] = sum_ch tpart[ch][m] ----------------
__global__ __launch_bounds__(256) void kred(const float* __restrict__ in,
                                            float* __restrict__ out) {
    int m = blockIdx.x * 256 + threadIdx.x;
    float acc = 0.f;
    #pragma unroll
    for (int ch = 0; ch < NCH; ++ch)
        acc += in[(size_t)ch * (BB * II * DD) + m];
    out[m] = acc;
}

// ---------------- big kernel: one routing pass, 8.3 KB LDS ----------------
__global__ __launch_bounds__(256) void kbig(const float* __restrict__ u,
                                            const float* __restrict__ w,
                                            float* __restrict__ tpart) {
    int b = blockIdx.y;
    int chunk = blockIdx.x;                 // 0..NCH-1
    int tid = threadIdx.x;
    int wv = tid >> 6, l = tid & 63, h = l >> 5, ln = l & 31;

    __shared__ float tlds[II][65];          // 8.3 KB — the ONLY LDS

    const float* ubase = u + (size_t)b * NN * DD;
    const float* wb    = w + (size_t)b * II * DD;
    int n0 = chunk * CHROWS + wv * 32;      // this wave's 32 rows

    // zero tlds early; barrier deferred until after independent compute
    for (int k = tid; k < II * 65; k += 256) (&tlds[0][0])[k] = 0.f;

    // ---- phase 1: C1[n][i] = sum_d u[n][d] * w~[i][d]  (A=u rows, B=w~^T) ----
    f32x16 S;
    #pragma unroll
    for (int r = 0; r < 16; ++r) S[r] = 0.f;
    #pragma unroll
    for (int kt = 0; kt < 4; ++kt) {
        int d0 = kt * 16 + h * 8;
        const float4* pa = reinterpret_cast<const float4*>(
            ubase + (size_t)(n0 + ln) * DD + d0);
        const float4* pb = reinterpret_cast<const float4*>(
            wb + (size_t)ln * DD + d0);
        float4 a0 = pa[0], a1 = pa[1];
        float4 b0 = pb[0], b1 = pb[1];
        bf16x8 A, Bv;
        A[0]=f2bf(a0.x); A[1]=f2bf(a0.y); A[2]=f2bf(a0.z); A[3]=f2bf(a0.w);
        A[4]=f2bf(a1.x); A[5]=f2bf(a1.y); A[6]=f2bf(a1.z); A[7]=f2bf(a1.w);
        Bv[0]=f2bf(b0.x); Bv[1]=f2bf(b0.y); Bv[2]=f2bf(b0.z); Bv[3]=f2bf(b0.w);
        Bv[4]=f2bf(b1.x); Bv[5]=f2bf(b1.y); Bv[6]=f2bf(b1.z); Bv[7]=f2bf(b1.w);
        S = __builtin_amdgcn_mfma_f32_32x32x16_bf16(A, Bv, S, 0, 0, 0);
    }

    // ---- softmax over i: cross-lane reduce within each 32-lane group.
    // C1 layout: col(=i) = l&31; row(=n_local) = (r&3)+8*(r>>2)+4*h.
    // shfl_xor offsets 1..16 stay inside the 32-group -> per-row reduce.
    float c[16];
    #pragma unroll
    for (int r = 0; r < 16; ++r) {
        float m = S[r];
        #pragma unroll
        for (int off = 1; off <= 16; off <<= 1) m = fmaxf(m, __shfl_xor(m, off));
        float e = __expf(S[r] - m);
        float s = e;
        #pragma unroll
        for (int off = 1; off <= 16; off <<= 1) s += __shfl_xor(s, off);
        c[r] = e / s;                       // c[n_r(h)][i=ln] in-register
    }

    // ---- phase 2: C2[i][d] = sum_n c[n][i]*u[n][d]; A=c^T from regs ----
    // A-frag (lane=row i=ln, k=n=t2*16+h*8+j): value c[n][ln] lives in
    // register r=(n&3)+4*(n>>3) of lane (ln + 32*((n>>2)&1)). For k-element j:
    // own register c[8*t2+j] when (j>>2)==h, else partner's reg (j^4) via
    // shfl_xor(.,32).
    f32x16 G0, G1;
    #pragma unroll
    for (int r = 0; r < 16; ++r) { G0[r] = 0.f; G1[r] = 0.f; }

    #pragma unroll
    for (int t2 = 0; t2 < 2; ++t2) {
        float pc[8];
        #pragma unroll
        for (int q = 0; q < 8; ++q) pc[q] = __shfl_xor(c[8 * t2 + q], 32);
        bf16x8 Ah, Al;
        #pragma unroll
        for (int j = 0; j < 8; ++j) {
            float av = ((j >> 2) == h) ? c[8 * t2 + j] : pc[j ^ 4];
            short hi = f2bf(av);
            Ah[j] = hi;
            Al[j] = f2bf(av - bf2f(hi));
        }
        #pragma unroll
        for (int Nt = 0; Nt < 2; ++Nt) {
            bf16x8 Bh, Bl;
            #pragma unroll
            for (int j = 0; j < 8; ++j) {
                int n = t2 * 16 + h * 8 + j;
                float uv = ubase[(size_t)(n0 + n) * DD + Nt * 32 + ln];  // u column
                short hi = f2bf(uv);
                Bh[j] = hi;
                Bl[j] = f2bf(uv - bf2f(hi));
            }
            if (Nt == 0) {
                G0 = __builtin_amdgcn_mfma_f32_32x32x16_bf16(Ah, Bh, G0, 0, 0, 0);
                G0 = __builtin_amdgcn_mfma_f32_32x32x16_bf16(Al, Bh, G0, 0, 0, 0);
                G0 = __builtin_amdgcn_mfma_f32_32x32x16_bf16(Ah, Bl, G0, 0, 0, 0);
            } else {
                G1 = __builtin_amdgcn_mfma_f32_32x32x16_bf16(Ah, Bh, G1, 0, 0, 0);
                G1 = __builtin_amdgcn_mfma_f32_32x32x16_bf16(Al, Bh, G1, 0, 0, 0);
                G1 = __builtin_amdgcn_mfma_f32_32x32x16_bf16(Ah, Bl, G1, 0, 0, 0);
            }
        }
    }

    // ---- cross-wave reduce + coalesced partial store ----
    __syncthreads();                        // tlds zeros visible
    #pragma unroll
    for (int r = 0; r < 16; ++r) {
        int irow = (r & 3) + 8 * (r >> 2) + 4 * h;
        atomicAdd(&tlds[irow][ln],      G0[r]);
        atomicAdd(&tlds[irow][32 + ln], G1[r]);
    }
    __syncthreads();
    float* dst = tpart + ((size_t)chunk * BB + b) * (II * DD);
    for (int k = tid; k < II * DD; k += 256)
        dst[k] = tlds[k >> 6][k & 63];
}

extern "C" void kernel_launch(void* const* d_in, const int* in_sizes, int n_in,
                              void* d_out, int out_size, void* d_ws, size_t ws_size,
                              hipStream_t stream) {
    const float* u = (const float*)d_in[0];     // (64, 2048, 64)
    const float* W = (const float*)d_in[1];     // (1, 64, 512)
    float* out = (float*)d_out;                 // (64, 32, 16)
    float* ws = (float*)d_ws;

    float* t1    = ws;                          // 131072 floats
    float* wtil  = ws + 131072;                 // 131072
    float* spart = ws + 2 * 131072;             // 131072
    float* tpart = ws + 3 * 131072;             // NCH*131072 (8 MB)

    dim3 gbig(NCH, BB);
    ksum<<<dim3(32, BB), 256, 0, stream>>>(u, spart);
    ksmall<0><<<BB, 512, 0, stream>>>(spart, W, wtil, nullptr);  // iter0
    kbig<<<gbig, 256, 0, stream>>>(u, wtil, tpart);
    kred<<<BB * II * DD / 256, 256, 0, stream>>>(tpart, t1);
    ksmall<1><<<BB, 512, 0, stream>>>(t1, W, wtil, nullptr);
    kbig<<<gbig, 256, 0, stream>>>(u, wtil, tpart);
    kred<<<BB * II * DD / 256, 256, 0, stream>>>(tpart, t1);
    ksmall<2><<<BB, 512, 0, stream>>>(t1, W, nullptr, out);      // squash
}